// Round 9
// baseline (53.229 us; speedup 1.0000x reference)
//
#include <hip/hip_runtime.h>
#include <math.h>

#define TRI_EPS 1e-4f

// ---------- prep ----------
// fdat6 (epilogue, VERBATIM layout): [a,inv1][b,inv2][c,inv3][e1][e2][e3]
// fdat5 (main, lean):                [a,inv1][c,inv2][e1,inv3][e2,0][e3,0]
__global__ __launch_bounds__(256) void prep_kernel(
    const float* __restrict__ v, const int* __restrict__ f,
    float4* __restrict__ fdat6, float4* __restrict__ fdat5,
    float* __restrict__ vm, int V, int F) {
    const int t = threadIdx.x;
    const int j = blockIdx.x * 256 + t;
    if (j < F) {
        const int i0 = f[3 * j + 0];
        const int i1 = f[3 * j + 1];
        const int i2 = f[3 * j + 2];
        const float ax = v[3 * i0 + 0], ay = v[3 * i0 + 1], az = v[3 * i0 + 2];
        const float bx = v[3 * i1 + 0], by = v[3 * i1 + 1], bz = v[3 * i1 + 2];
        const float cx = v[3 * i2 + 0], cy = v[3 * i2 + 1], cz = v[3 * i2 + 2];
        const float e1x = ax - bx, e1y = ay - by, e1z = az - bz;
        const float e2x = cx - bx, e2y = cy - by, e2z = cz - bz;
        const float e3x = cx - ax, e3y = cy - ay, e3z = cz - az;
        const float m1 = e1x * e1x + e1y * e1y + e1z * e1z;
        const float m2 = e2x * e2x + e2y * e2y + e2z * e2z;
        const float m3 = e3x * e3x + e3y * e3y + e3z * e3z;
        const float inv1 = 1.f / m1, inv2 = 1.f / m2, inv3 = 1.f / m3;
        fdat6[6 * j + 0] = make_float4(ax, ay, az, inv1);
        fdat6[6 * j + 1] = make_float4(bx, by, bz, inv2);
        fdat6[6 * j + 2] = make_float4(cx, cy, cz, inv3);
        fdat6[6 * j + 3] = make_float4(e1x, e1y, e1z, 0.f);
        fdat6[6 * j + 4] = make_float4(e2x, e2y, e2z, 0.f);
        fdat6[6 * j + 5] = make_float4(e3x, e3y, e3z, 0.f);
        fdat5[5 * j + 0] = make_float4(ax, ay, az, inv1);
        fdat5[5 * j + 1] = make_float4(cx, cy, cz, inv2);
        fdat5[5 * j + 2] = make_float4(e1x, e1y, e1z, inv3);
        fdat5[5 * j + 3] = make_float4(e2x, e2y, e2z, 0.f);
        fdat5[5 * j + 4] = make_float4(e3x, e3y, e3z, 0.f);
    }
    if (blockIdx.x == 0) {
        __shared__ float sx[256], sy[256], sz[256];
        float x = 0.f, y = 0.f, z = 0.f;
        for (int i = t; i < V; i += 256) {
            x += v[3 * i + 0];
            y += v[3 * i + 1];
            z += v[3 * i + 2];
        }
        sx[t] = x; sy[t] = y; sz[t] = z;
        __syncthreads();
        for (int off = 128; off > 0; off >>= 1) {
            if (t < off) {
                sx[t] += sx[t + off];
                sy[t] += sy[t + off];
                sz[t] += sz[t + off];
            }
            __syncthreads();
        }
        if (t == 0) {
            vm[0] = sx[0] / (float)V;
            vm[1] = sy[0] / (float)V;
            vm[2] = sz[0] / (float)V;
        }
    }
}

// ---------- verbatim face_point (epilogue only — bit-stable since R2) ------
struct FP {
    float d1, d2, d3;
    float x1, y1, z1, x2, y2, z2, x3, y3, z3;
    float apx, apy, apz;
};

__device__ __forceinline__ FP face_point(
    const float4 ra, const float4 rb, const float4 rc,
    const float e1x, const float e1y, const float e1z,
    const float e2x, const float e2y, const float e2z,
    const float e3x, const float e3y, const float e3z,
    const float px, const float py, const float pz) {
    FP r;
    const float ax = ra.x, ay = ra.y, az = ra.z;
    const float bx = rb.x, by = rb.y, bz = rb.z;
    const float cx = rc.x, cy = rc.y, cz = rc.z;
    r.apx = ax - px; r.apy = ay - py; r.apz = az - pz;
    const float cpx = cx - px, cpy = cy - py, cpz = cz - pz;

    float s1 = (r.apx * e1x + r.apy * e1y + r.apz * e1z) * ra.w;
    s1 = fminf(fmaxf(s1, 0.f), 1.f);
    const float o1 = 1.f - s1;
    r.x1 = s1 * bx + o1 * ax;
    r.y1 = s1 * by + o1 * ay;
    r.z1 = s1 * bz + o1 * az;
    float ux = r.x1 - px, uy = r.y1 - py, uz = r.z1 - pz;
    r.d1 = ux * ux + uy * uy + uz * uz;

    float s2 = (cpx * e2x + cpy * e2y + cpz * e2z) * rb.w;
    s2 = fminf(fmaxf(s2, 0.f), 1.f);
    const float o2 = 1.f - s2;
    r.x2 = s2 * bx + o2 * cx;
    r.y2 = s2 * by + o2 * cy;
    r.z2 = s2 * bz + o2 * cz;
    ux = r.x2 - px; uy = r.y2 - py; uz = r.z2 - pz;
    r.d2 = ux * ux + uy * uy + uz * uz;

    float s3 = (cpx * e3x + cpy * e3y + cpz * e3z) * rc.w;
    s3 = fminf(fmaxf(s3, 0.f), 1.f);
    const float o3 = 1.f - s3;
    r.x3 = s3 * ax + o3 * cx;
    r.y3 = s3 * ay + o3 * cy;
    r.z3 = s3 * az + o3 * cz;
    ux = r.x3 - px; uy = r.y3 - py; uz = r.z3 - pz;
    r.d3 = ux * ux + uy * uy + uz * uz;
    return r;
}

// ---------- lean per-pair update: d^2 only + verbatim MT -------------------
__device__ __forceinline__ void pair_lean(
    const float4 r0, const float4 r1, const float4 r2,
    const float4 r3, const float4 r4,
    const float px, const float py, const float pz,
    const float dx, const float dy, const float dz, const int j,
    float& bd2, int& bid, int& hits) {
    const float apx = r0.x - px, apy = r0.y - py, apz = r0.z - pz;
    const float cpx = r1.x - px, cpy = r1.y - py, cpz = r1.z - pz;
    const float e1x = r2.x, e1y = r2.y, e1z = r2.z;
    const float e2x = r3.x, e2y = r3.y, e2z = r3.z;
    const float e3x = r4.x, e3y = r4.y, e3z = r4.z;

    float s1 = (apx * e1x + apy * e1y + apz * e1z) * r0.w;
    s1 = fminf(fmaxf(s1, 0.f), 1.f);
    const float u1x = apx - s1 * e1x;
    const float u1y = apy - s1 * e1y;
    const float u1z = apz - s1 * e1z;
    const float d1 = u1x * u1x + u1y * u1y + u1z * u1z;

    float s2 = (cpx * e2x + cpy * e2y + cpz * e2z) * r1.w;
    s2 = fminf(fmaxf(s2, 0.f), 1.f);
    const float u2x = cpx - s2 * e2x;
    const float u2y = cpy - s2 * e2y;
    const float u2z = cpz - s2 * e2z;
    const float d2 = u2x * u2x + u2y * u2y + u2z * u2z;

    float s3 = (cpx * e3x + cpy * e3y + cpz * e3z) * r2.w;
    s3 = fminf(fmaxf(s3, 0.f), 1.f);
    const float u3x = cpx - s3 * e3x;
    const float u3y = cpy - s3 * e3y;
    const float u3z = cpz - s3 * e3z;
    const float d3 = u3x * u3x + u3y * u3y + u3z * u3z;

    float fd2 = d1; int eid = 0;
    if (d2 < fd2) { fd2 = d2; eid = 1; }
    if (d3 < fd2) { fd2 = d3; eid = 2; }
    if (fd2 < bd2) { bd2 = fd2; bid = (j << 2) | eid; }

    // Moller-Trumbore (VERBATIM — parity must not move)
    const float pvx = dy * e3z - dz * e3y;
    const float pvy = dz * e3x - dx * e3z;
    const float pvz = dx * e3y - dy * e3x;
    const float det = -(e1x * pvx + e1y * pvy + e1z * pvz);
    const float tu = -(apx * pvx + apy * pvy + apz * pvz);
    const float qvx = apy * e1z - apz * e1y;
    const float qvy = apz * e1x - apx * e1z;
    const float qvz = apx * e1y - apy * e1x;
    const float td = dx * qvx + dy * qvy + dz * qvz;
    const float tn = e3x * qvx + e3y * qvy + e3z * qvz;
    const float adet = fabsf(det);
    const float sd = (det > 0.f) ? 1.f : -1.f;
    const float su = tu * sd;
    const float sq = td * sd;
    const float st = tn * sd;
    if (adet > TRI_EPS && su >= 0.f && su <= adet && sq >= 0.f &&
        (su + sq) <= adet && st > TRI_EPS * adet)
        hits++;
}

// ---------- main: 2 pts/lane (dual dep-chains), LDS faces, no atomics ------
template <int CS>
__global__ __launch_bounds__(256) void sdf_main2_t(
    const float* __restrict__ p, const float4* __restrict__ fd5,
    const float* __restrict__ vm,
    unsigned long long* __restrict__ keysP, unsigned* __restrict__ hitsP,
    int N, int C) {
    __shared__ float4 sfd[5 * CS];
    const int t = threadIdx.x;
    const int k = blockIdx.x % C;
    const int pg = blockIdx.x / C;
    const int j0 = k * CS;

    if (t < 5 * CS) sfd[t] = fd5[5 * j0 + t];

    const int iA = pg * 512 + t;
    const int iB = iA + 256;
    const bool vA = (iA < N);
    const bool vB = (iB < N);
    const int lA = vA ? iA : 0;
    const int lB = vB ? iB : 0;
    const float pAx = p[3 * lA + 0], pAy = p[3 * lA + 1], pAz = p[3 * lA + 2];
    const float pBx = p[3 * lB + 0], pBy = p[3 * lB + 1], pBz = p[3 * lB + 2];
    const float vmx = vm[0], vmy = vm[1], vmz = vm[2];
    const float dAx = vmx - pAx, dAy = vmy - pAy, dAz = vmz - pAz;
    const float dBx = vmx - pBx, dBy = vmy - pBy, dBz = vmz - pBz;

    float Ad2 = INFINITY; int Aid = 0x7fffffff; int Ah = 0;
    float Bd2 = INFINITY; int Bid = 0x7fffffff; int Bh = 0;

    __syncthreads();

    #pragma unroll 2
    for (int jj = 0; jj < CS; ++jj) {
        const float4 r0 = sfd[5 * jj + 0];
        const float4 r1 = sfd[5 * jj + 1];
        const float4 r2 = sfd[5 * jj + 2];
        const float4 r3 = sfd[5 * jj + 3];
        const float4 r4 = sfd[5 * jj + 4];
        const int j = j0 + jj;
        pair_lean(r0, r1, r2, r3, r4, pAx, pAy, pAz, dAx, dAy, dAz, j,
                  Ad2, Aid, Ah);
        pair_lean(r0, r1, r2, r3, r4, pBx, pBy, pBz, dBx, dBy, dBz, j,
                  Bd2, Bid, Bh);
    }

    if (vA) {
        keysP[(size_t)k * N + iA] =
            ((unsigned long long)__float_as_uint(Ad2) << 32) | (unsigned int)Aid;
        hitsP[(size_t)k * N + iA] = (unsigned)Ah;
    }
    if (vB) {
        keysP[(size_t)k * N + iB] =
            ((unsigned long long)__float_as_uint(Bd2) << 32) | (unsigned int)Bid;
        hitsP[(size_t)k * N + iB] = (unsigned)Bh;
    }
}

// ---------- generic fallback (runtime CS, global loads, 1 pt/lane) ---------
__global__ __launch_bounds__(256) void sdf_main_g(
    const float* __restrict__ p, const float4* __restrict__ fd5,
    const float* __restrict__ vm,
    unsigned long long* __restrict__ keysP, unsigned* __restrict__ hitsP,
    int N, int F, int C, int CS) {
    const int k = blockIdx.x % C;
    const int pg = blockIdx.x / C;
    const int i = pg * 256 + threadIdx.x;
    if (i >= N) return;
    const float px = p[3 * i + 0];
    const float py = p[3 * i + 1];
    const float pz = p[3 * i + 2];
    const float dx = vm[0] - px;
    const float dy = vm[1] - py;
    const float dz = vm[2] - pz;
    float bd2 = INFINITY; int bid = 0x7fffffff; int hits = 0;
    const int j0 = k * CS;
    const int j1 = min(F, j0 + CS);
    for (int j = j0; j < j1; ++j) {
        pair_lean(fd5[5 * j + 0], fd5[5 * j + 1], fd5[5 * j + 2],
                  fd5[5 * j + 3], fd5[5 * j + 4],
                  px, py, pz, dx, dy, dz, j, bd2, bid, hits);
    }
    keysP[(size_t)k * N + i] =
        ((unsigned long long)__float_as_uint(bd2) << 32) | (unsigned int)bid;
    hitsP[(size_t)k * N + i] = (unsigned)hits;
}

// ---------- reduce over chunks + verbatim epilogue, parallel ---------------
__global__ __launch_bounds__(256) void sdf_reduce_epi(
    const float* __restrict__ p, const float4* __restrict__ fd6,
    const unsigned long long* __restrict__ keysP,
    const unsigned* __restrict__ hitsP,
    float* __restrict__ out, int N, int C) {
    const int t = threadIdx.x;
    const int q = t & 63;
    const int w = t >> 6;
    const int i = blockIdx.x * 64 + q;

    unsigned long long bk = 0xFFFFFFFFFFFFFFFFull;
    unsigned hs = 0;
    if (i < N) {
        const int kpw = C >> 2;
        int k = w * kpw;
        #pragma unroll 4
        for (int kk = 0; kk < kpw; ++kk, ++k) {
            const unsigned long long kv = keysP[(size_t)k * N + i];
            if (kv < bk) bk = kv;
            hs += hitsP[(size_t)k * N + i];
        }
    }
    __shared__ unsigned long long sk[4][64];
    __shared__ unsigned sh[4][64];
    sk[w][q] = bk;
    sh[w][q] = hs;
    __syncthreads();
    if (w == 0 && i < N) {
        #pragma unroll
        for (int ww = 1; ww < 4; ++ww) {
            const unsigned long long kv = sk[ww][q];
            if (kv < bk) bk = kv;
            hs += sh[ww][q];
        }
        const float bd2 = __uint_as_float((unsigned int)(bk >> 32));
        const int bid = (int)(unsigned int)(bk & 0xFFFFFFFFull);
        const int jw = bid >> 2;
        const int eid = bid & 3;
        const float px = p[3 * i + 0];
        const float py = p[3 * i + 1];
        const float pz = p[3 * i + 2];
        const float4 wa  = fd6[6 * jw + 0];
        const float4 wb  = fd6[6 * jw + 1];
        const float4 wc  = fd6[6 * jw + 2];
        const float4 we1 = fd6[6 * jw + 3];
        const float4 we2 = fd6[6 * jw + 4];
        const float4 we3 = fd6[6 * jw + 5];
        const FP r = face_point(wa, wb, wc, we1.x, we1.y, we1.z,
                                we2.x, we2.y, we2.z, we3.x, we3.y, we3.z,
                                px, py, pz);
        float clx = r.x1, cly = r.y1, clz = r.z1;
        if (eid == 1) { clx = r.x2; cly = r.y2; clz = r.z2; }
        if (eid == 2) { clx = r.x3; cly = r.y3; clz = r.z3; }
        const float d = sqrtf(bd2);
        out[i] = (hs & 1u) ? -d : d;
        out[N + 3 * i + 0] = clx;
        out[N + 3 * i + 1] = cly;
        out[N + 3 * i + 2] = clz;
    }
}

extern "C" void kernel_launch(void* const* d_in, const int* in_sizes, int n_in,
                              void* d_out, int out_size, void* d_ws,
                              size_t ws_size, hipStream_t stream) {
    const float* p = (const float*)d_in[0];
    const float* v = (const float*)d_in[1];
    const int* f = (const int*)d_in[2];
    float* out = (float*)d_out;

    const int N = in_sizes[0] / 3;
    const int V = in_sizes[1] / 3;
    const int F = in_sizes[2] / 3;

    const int C = 512;  // face chunks (multiple of 4 for reduce)
    const int CS = 8;   // faces per chunk (template path when F == C*CS)

    // ws: vm[4] | keysP[C*N] u64 | hitsP[C*N] u32 | fdat6[6F] | fdat5[5F]
    char* base = (char*)d_ws;
    float* vm = (float*)base;
    unsigned long long* keysP = (unsigned long long*)(base + 16);
    unsigned* hitsP = (unsigned*)(base + 16 + 8ull * C * N);
    size_t off = 16 + 12ull * C * N;
    off = (off + 15) & ~15ull;
    float4* fdat6 = (float4*)(base + off);
    float4* fdat5 = (float4*)(base + off + 6ull * F * sizeof(float4));

    prep_kernel<<<(F + 255) / 256, 256, 0, stream>>>(v, f, fdat6, fdat5, vm,
                                                     V, F);

    if (F == C * CS) {
        const int npg = (N + 511) / 512;
        sdf_main2_t<CS><<<npg * C, 256, 0, stream>>>(p, fdat5, vm, keysP,
                                                     hitsP, N, C);
    } else {
        const int CSg = (F + C - 1) / C;
        const int npg = (N + 255) / 256;
        sdf_main_g<<<npg * C, 256, 0, stream>>>(p, fdat5, vm, keysP, hitsP,
                                                N, F, C, CSg);
    }
    sdf_reduce_epi<<<(N + 63) / 64, 256, 0, stream>>>(p, fdat6, keysP, hitsP,
                                                      out, N, C);
}

// Round 10
// 47.164 us; speedup vs baseline: 1.1286x; 1.1286x over previous
//
#include <hip/hip_runtime.h>
#include <math.h>

#define TRI_EPS 1e-4f

// ---------- prep (verbatim R8) ----------
__global__ __launch_bounds__(256) void prep_kernel(
    const float* __restrict__ v, const int* __restrict__ f,
    float4* __restrict__ fdat6, float4* __restrict__ fdat5,
    float* __restrict__ vm, int V, int F) {
    const int t = threadIdx.x;
    const int j = blockIdx.x * 256 + t;
    if (j < F) {
        const int i0 = f[3 * j + 0];
        const int i1 = f[3 * j + 1];
        const int i2 = f[3 * j + 2];
        const float ax = v[3 * i0 + 0], ay = v[3 * i0 + 1], az = v[3 * i0 + 2];
        const float bx = v[3 * i1 + 0], by = v[3 * i1 + 1], bz = v[3 * i1 + 2];
        const float cx = v[3 * i2 + 0], cy = v[3 * i2 + 1], cz = v[3 * i2 + 2];
        const float e1x = ax - bx, e1y = ay - by, e1z = az - bz;
        const float e2x = cx - bx, e2y = cy - by, e2z = cz - bz;
        const float e3x = cx - ax, e3y = cy - ay, e3z = cz - az;
        const float m1 = e1x * e1x + e1y * e1y + e1z * e1z;
        const float m2 = e2x * e2x + e2y * e2y + e2z * e2z;
        const float m3 = e3x * e3x + e3y * e3y + e3z * e3z;
        const float inv1 = 1.f / m1, inv2 = 1.f / m2, inv3 = 1.f / m3;
        fdat6[6 * j + 0] = make_float4(ax, ay, az, inv1);
        fdat6[6 * j + 1] = make_float4(bx, by, bz, inv2);
        fdat6[6 * j + 2] = make_float4(cx, cy, cz, inv3);
        fdat6[6 * j + 3] = make_float4(e1x, e1y, e1z, 0.f);
        fdat6[6 * j + 4] = make_float4(e2x, e2y, e2z, 0.f);
        fdat6[6 * j + 5] = make_float4(e3x, e3y, e3z, 0.f);
        fdat5[5 * j + 0] = make_float4(ax, ay, az, inv1);
        fdat5[5 * j + 1] = make_float4(cx, cy, cz, inv2);
        fdat5[5 * j + 2] = make_float4(e1x, e1y, e1z, inv3);
        fdat5[5 * j + 3] = make_float4(e2x, e2y, e2z, 0.f);
        fdat5[5 * j + 4] = make_float4(e3x, e3y, e3z, 0.f);
    }
    if (blockIdx.x == 0) {
        __shared__ float sx[256], sy[256], sz[256];
        float x = 0.f, y = 0.f, z = 0.f;
        for (int i = t; i < V; i += 256) {
            x += v[3 * i + 0];
            y += v[3 * i + 1];
            z += v[3 * i + 2];
        }
        sx[t] = x; sy[t] = y; sz[t] = z;
        __syncthreads();
        for (int off = 128; off > 0; off >>= 1) {
            if (t < off) {
                sx[t] += sx[t + off];
                sy[t] += sy[t + off];
                sz[t] += sz[t + off];
            }
            __syncthreads();
        }
        if (t == 0) {
            vm[0] = sx[0] / (float)V;
            vm[1] = sy[0] / (float)V;
            vm[2] = sz[0] / (float)V;
        }
    }
}

// ---------- verbatim face_point (epilogue only — bit-stable since R2) ------
struct FP {
    float d1, d2, d3;
    float x1, y1, z1, x2, y2, z2, x3, y3, z3;
    float apx, apy, apz;
};

__device__ __forceinline__ FP face_point(
    const float4 ra, const float4 rb, const float4 rc,
    const float e1x, const float e1y, const float e1z,
    const float e2x, const float e2y, const float e2z,
    const float e3x, const float e3y, const float e3z,
    const float px, const float py, const float pz) {
    FP r;
    const float ax = ra.x, ay = ra.y, az = ra.z;
    const float bx = rb.x, by = rb.y, bz = rb.z;
    const float cx = rc.x, cy = rc.y, cz = rc.z;
    r.apx = ax - px; r.apy = ay - py; r.apz = az - pz;
    const float cpx = cx - px, cpy = cy - py, cpz = cz - pz;

    float s1 = (r.apx * e1x + r.apy * e1y + r.apz * e1z) * ra.w;
    s1 = fminf(fmaxf(s1, 0.f), 1.f);
    const float o1 = 1.f - s1;
    r.x1 = s1 * bx + o1 * ax;
    r.y1 = s1 * by + o1 * ay;
    r.z1 = s1 * bz + o1 * az;
    float ux = r.x1 - px, uy = r.y1 - py, uz = r.z1 - pz;
    r.d1 = ux * ux + uy * uy + uz * uz;

    float s2 = (cpx * e2x + cpy * e2y + cpz * e2z) * rb.w;
    s2 = fminf(fmaxf(s2, 0.f), 1.f);
    const float o2 = 1.f - s2;
    r.x2 = s2 * bx + o2 * cx;
    r.y2 = s2 * by + o2 * cy;
    r.z2 = s2 * bz + o2 * cz;
    ux = r.x2 - px; uy = r.y2 - py; uz = r.z2 - pz;
    r.d2 = ux * ux + uy * uy + uz * uz;

    float s3 = (cpx * e3x + cpy * e3y + cpz * e3z) * rc.w;
    s3 = fminf(fmaxf(s3, 0.f), 1.f);
    const float o3 = 1.f - s3;
    r.x3 = s3 * ax + o3 * cx;
    r.y3 = s3 * ay + o3 * cy;
    r.z3 = s3 * az + o3 * cz;
    ux = r.x3 - px; uy = r.y3 - py; uz = r.z3 - pz;
    r.d3 = ux * ux + uy * uy + uz * uz;
    return r;
}

// lean pair (verbatim expressions from R8) — used by generic fallback
__device__ __forceinline__ void pair_lean(
    const float4 r0, const float4 r1, const float4 r2,
    const float4 r3, const float4 r4,
    const float px, const float py, const float pz,
    const float dx, const float dy, const float dz, const int j,
    float& bd2, int& bid, int& hits) {
    const float apx = r0.x - px, apy = r0.y - py, apz = r0.z - pz;
    const float cpx = r1.x - px, cpy = r1.y - py, cpz = r1.z - pz;
    const float e1x = r2.x, e1y = r2.y, e1z = r2.z;
    const float e2x = r3.x, e2y = r3.y, e2z = r3.z;
    const float e3x = r4.x, e3y = r4.y, e3z = r4.z;

    float s1 = (apx * e1x + apy * e1y + apz * e1z) * r0.w;
    s1 = fminf(fmaxf(s1, 0.f), 1.f);
    const float u1x = apx - s1 * e1x;
    const float u1y = apy - s1 * e1y;
    const float u1z = apz - s1 * e1z;
    const float d1 = u1x * u1x + u1y * u1y + u1z * u1z;

    float s2 = (cpx * e2x + cpy * e2y + cpz * e2z) * r1.w;
    s2 = fminf(fmaxf(s2, 0.f), 1.f);
    const float u2x = cpx - s2 * e2x;
    const float u2y = cpy - s2 * e2y;
    const float u2z = cpz - s2 * e2z;
    const float d2 = u2x * u2x + u2y * u2y + u2z * u2z;

    float s3 = (cpx * e3x + cpy * e3y + cpz * e3z) * r2.w;
    s3 = fminf(fmaxf(s3, 0.f), 1.f);
    const float u3x = cpx - s3 * e3x;
    const float u3y = cpy - s3 * e3y;
    const float u3z = cpz - s3 * e3z;
    const float d3 = u3x * u3x + u3y * u3y + u3z * u3z;

    float fd2 = d1; int eid = 0;
    if (d2 < fd2) { fd2 = d2; eid = 1; }
    if (d3 < fd2) { fd2 = d3; eid = 2; }
    if (fd2 < bd2) { bd2 = fd2; bid = (j << 2) | eid; }

    const float pvx = dy * e3z - dz * e3y;
    const float pvy = dz * e3x - dx * e3z;
    const float pvz = dx * e3y - dy * e3x;
    const float det = -(e1x * pvx + e1y * pvy + e1z * pvz);
    const float tu = -(apx * pvx + apy * pvy + apz * pvz);
    const float qvx = apy * e1z - apz * e1y;
    const float qvy = apz * e1x - apx * e1z;
    const float qvz = apx * e1y - apy * e1x;
    const float td = dx * qvx + dy * qvy + dz * qvz;
    const float tn = e3x * qvx + e3y * qvy + e3z * qvz;
    const float adet = fabsf(det);
    const float sd = (det > 0.f) ? 1.f : -1.f;
    const float su = tu * sd;
    const float sq = td * sd;
    const float st = tn * sd;
    if (adet > TRI_EPS && su >= 0.f && su <= adet && sq >= 0.f &&
        (su + sq) <= adet && st > TRI_EPS * adet)
        hits++;
}

#define SWZF(x, imm) \
    __int_as_float(__builtin_amdgcn_ds_swizzle(__float_as_int(x), imm))

// ---------- transposed main: lane = face (regs), iterate points ------------
// partials per 16-lane face group: g = j>>4 in [0, F/16); layout g*N + pt.
template <int PC>
__global__ __launch_bounds__(256, 8) void sdf_tr(
    const float* __restrict__ p, const float4* __restrict__ fd5,
    const float* __restrict__ vm,
    unsigned long long* __restrict__ keysP, unsigned* __restrict__ hitsP,
    int N, int FB) {
    const int t = threadIdx.x;
    const int b = blockIdx.x;
    const int fb = b % FB;        // face block (256 faces)
    const int pc = b / FB;        // point chunk (PC points)
    const int j = fb * 256 + t;   // this lane's face (F % 256 == 0)

    // face data -> registers, once
    const float4 r0 = fd5[5 * j + 0];
    const float4 r1 = fd5[5 * j + 1];
    const float4 r2 = fd5[5 * j + 2];
    const float4 r3 = fd5[5 * j + 3];
    const float4 r4 = fd5[5 * j + 4];
    const float ax = r0.x, ay = r0.y, az = r0.z, inv1 = r0.w;
    const float cx = r1.x, cy = r1.y, cz = r1.z, inv2 = r1.w;
    const float e1x = r2.x, e1y = r2.y, e1z = r2.z, inv3 = r2.w;
    const float e2x = r3.x, e2y = r3.y, e2z = r3.z;
    const float e3x = r4.x, e3y = r4.y, e3z = r4.z;

    const float vmx = vm[0], vmy = vm[1], vmz = vm[2];

    __shared__ float4 spt[PC];
    if (t < 4 * PC) {
        const int idx = t >> 2, c = t & 3;
        const int gi = pc * PC + idx;
        float val = 0.f;
        if (c < 3 && gi < N) val = p[3 * gi + c];
        ((float*)spt)[t] = val;
    }
    __syncthreads();

    const int bid_base = (j << 2);
    const int sh = t & 48;  // 16-lane group shift within wave

    for (int it = 0; it < PC; ++it) {
        const int pt = pc * PC + it;
        const float4 P = spt[it];
        const float px = P.x, py = P.y, pz = P.z;
        const float dx = vmx - px, dy = vmy - py, dz = vmz - pz;

        // ---- lean distances (verbatim R8 expressions) ----
        const float apx = ax - px, apy = ay - py, apz = az - pz;
        const float cpx = cx - px, cpy = cy - py, cpz = cz - pz;

        float s1 = (apx * e1x + apy * e1y + apz * e1z) * inv1;
        s1 = fminf(fmaxf(s1, 0.f), 1.f);
        const float u1x = apx - s1 * e1x;
        const float u1y = apy - s1 * e1y;
        const float u1z = apz - s1 * e1z;
        const float d1 = u1x * u1x + u1y * u1y + u1z * u1z;

        float s2 = (cpx * e2x + cpy * e2y + cpz * e2z) * inv2;
        s2 = fminf(fmaxf(s2, 0.f), 1.f);
        const float u2x = cpx - s2 * e2x;
        const float u2y = cpy - s2 * e2y;
        const float u2z = cpz - s2 * e2z;
        const float d2 = u2x * u2x + u2y * u2y + u2z * u2z;

        float s3 = (cpx * e3x + cpy * e3y + cpz * e3z) * inv3;
        s3 = fminf(fmaxf(s3, 0.f), 1.f);
        const float u3x = cpx - s3 * e3x;
        const float u3y = cpy - s3 * e3y;
        const float u3z = cpz - s3 * e3z;
        const float d3 = u3x * u3x + u3y * u3y + u3z * u3z;

        float fd2 = d1; int eid = 0;
        if (d2 < fd2) { fd2 = d2; eid = 1; }
        if (d3 < fd2) { fd2 = d3; eid = 2; }

        // ---- Moller-Trumbore (VERBATIM) ----
        const float pvx = dy * e3z - dz * e3y;
        const float pvy = dz * e3x - dx * e3z;
        const float pvz = dx * e3y - dy * e3x;
        const float det = -(e1x * pvx + e1y * pvy + e1z * pvz);
        const float tu = -(apx * pvx + apy * pvy + apz * pvz);
        const float qvx = apy * e1z - apz * e1y;
        const float qvy = apz * e1x - apx * e1z;
        const float qvz = apx * e1y - apy * e1x;
        const float td = dx * qvx + dy * qvy + dz * qvz;
        const float tn = e3x * qvx + e3y * qvy + e3z * qvz;
        const float adet = fabsf(det);
        const float sd = (det > 0.f) ? 1.f : -1.f;
        const float su = tu * sd;
        const float sq = td * sd;
        const float st = tn * sd;
        const int hit = (adet > TRI_EPS && su >= 0.f && su <= adet &&
                         sq >= 0.f && (su + sq) <= adet &&
                         st > TRI_EPS * adet) ? 1 : 0;

        // ---- 16-lane-group reduce: exact lex-min of (d2, id), hit count ---
        float dmin = fd2;
        dmin = fminf(dmin, SWZF(dmin, 0x041F));
        dmin = fminf(dmin, SWZF(dmin, 0x081F));
        dmin = fminf(dmin, SWZF(dmin, 0x101F));
        dmin = fminf(dmin, SWZF(dmin, 0x201F));
        int idv = (fd2 == dmin) ? (bid_base | eid) : 0x7fffffff;
        idv = min(idv, __builtin_amdgcn_ds_swizzle(idv, 0x041F));
        idv = min(idv, __builtin_amdgcn_ds_swizzle(idv, 0x081F));
        idv = min(idv, __builtin_amdgcn_ds_swizzle(idv, 0x101F));
        idv = min(idv, __builtin_amdgcn_ds_swizzle(idv, 0x201F));
        const unsigned long long bal = __ballot(hit);
        const unsigned hcount = (unsigned)__popcll((bal >> sh) & 0xFFFFull);

        if (((t & 15) == 0) && pt < N) {
            const int g = (j >> 4);
            keysP[(size_t)g * N + pt] =
                ((unsigned long long)__float_as_uint(dmin) << 32) |
                (unsigned int)idv;
            hitsP[(size_t)g * N + pt] = hcount;
        }
    }
}

// ---------- generic fallback (runtime CS, 1 pt/lane, C chunks) -------------
__global__ __launch_bounds__(256) void sdf_main_g(
    const float* __restrict__ p, const float4* __restrict__ fd5,
    const float* __restrict__ vm,
    unsigned long long* __restrict__ keysP, unsigned* __restrict__ hitsP,
    int N, int F, int C, int CS) {
    const int k = blockIdx.x % C;
    const int pg = blockIdx.x / C;
    const int i = pg * 256 + threadIdx.x;
    if (i >= N) return;
    const float px = p[3 * i + 0];
    const float py = p[3 * i + 1];
    const float pz = p[3 * i + 2];
    const float dx = vm[0] - px;
    const float dy = vm[1] - py;
    const float dz = vm[2] - pz;
    float bd2 = INFINITY; int bid = 0x7fffffff; int hits = 0;
    const int j0 = k * CS;
    const int j1 = min(F, j0 + CS);
    for (int j = j0; j < j1; ++j) {
        pair_lean(fd5[5 * j + 0], fd5[5 * j + 1], fd5[5 * j + 2],
                  fd5[5 * j + 3], fd5[5 * j + 4],
                  px, py, pz, dx, dy, dz, j, bd2, bid, hits);
    }
    keysP[(size_t)k * N + i] =
        ((unsigned long long)__float_as_uint(bd2) << 32) | (unsigned int)bid;
    hitsP[(size_t)k * N + i] = (unsigned)hits;
}

// ---------- reduce over chunks + verbatim epilogue (R8, C=256) -------------
__global__ __launch_bounds__(256) void sdf_reduce_epi(
    const float* __restrict__ p, const float4* __restrict__ fd6,
    const unsigned long long* __restrict__ keysP,
    const unsigned* __restrict__ hitsP,
    float* __restrict__ out, int N, int C) {
    const int t = threadIdx.x;
    const int q = t & 63;
    const int w = t >> 6;
    const int i = blockIdx.x * 64 + q;

    unsigned long long bk = 0xFFFFFFFFFFFFFFFFull;
    unsigned hs = 0;
    if (i < N) {
        const int kpw = C >> 2;
        int k = w * kpw;
        #pragma unroll 4
        for (int kk = 0; kk < kpw; ++kk, ++k) {
            const unsigned long long kv = keysP[(size_t)k * N + i];
            if (kv < bk) bk = kv;
            hs += hitsP[(size_t)k * N + i];
        }
    }
    __shared__ unsigned long long sk[4][64];
    __shared__ unsigned sh[4][64];
    sk[w][q] = bk;
    sh[w][q] = hs;
    __syncthreads();
    if (w == 0 && i < N) {
        #pragma unroll
        for (int ww = 1; ww < 4; ++ww) {
            const unsigned long long kv = sk[ww][q];
            if (kv < bk) bk = kv;
            hs += sh[ww][q];
        }
        const float bd2 = __uint_as_float((unsigned int)(bk >> 32));
        const int bid = (int)(unsigned int)(bk & 0xFFFFFFFFull);
        const int jw = bid >> 2;
        const int eid = bid & 3;
        const float px = p[3 * i + 0];
        const float py = p[3 * i + 1];
        const float pz = p[3 * i + 2];
        const float4 wa  = fd6[6 * jw + 0];
        const float4 wb  = fd6[6 * jw + 1];
        const float4 wc  = fd6[6 * jw + 2];
        const float4 we1 = fd6[6 * jw + 3];
        const float4 we2 = fd6[6 * jw + 4];
        const float4 we3 = fd6[6 * jw + 5];
        const FP r = face_point(wa, wb, wc, we1.x, we1.y, we1.z,
                                we2.x, we2.y, we2.z, we3.x, we3.y, we3.z,
                                px, py, pz);
        float clx = r.x1, cly = r.y1, clz = r.z1;
        if (eid == 1) { clx = r.x2; cly = r.y2; clz = r.z2; }
        if (eid == 2) { clx = r.x3; cly = r.y3; clz = r.z3; }
        const float d = sqrtf(bd2);
        out[i] = (hs & 1u) ? -d : d;
        out[N + 3 * i + 0] = clx;
        out[N + 3 * i + 1] = cly;
        out[N + 3 * i + 2] = clz;
    }
}

extern "C" void kernel_launch(void* const* d_in, const int* in_sizes, int n_in,
                              void* d_out, int out_size, void* d_ws,
                              size_t ws_size, hipStream_t stream) {
    const float* p = (const float*)d_in[0];
    const float* v = (const float*)d_in[1];
    const int* f = (const int*)d_in[2];
    float* out = (float*)d_out;

    const int N = in_sizes[0] / 3;
    const int V = in_sizes[1] / 3;
    const int F = in_sizes[2] / 3;

    // ws: vm[4] | keysP[C*N] u64 | hitsP[C*N] u32 | fdat6[6F] | fdat5[5F]
    const int C = (F % 256 == 0) ? (F / 16) : 256;  // partial chunks
    char* base = (char*)d_ws;
    float* vm = (float*)base;
    unsigned long long* keysP = (unsigned long long*)(base + 16);
    unsigned* hitsP = (unsigned*)(base + 16 + 8ull * C * N);
    size_t off = 16 + 12ull * C * N;
    off = (off + 15) & ~15ull;
    float4* fdat6 = (float4*)(base + off);
    float4* fdat5 = (float4*)(base + off + 6ull * F * sizeof(float4));

    prep_kernel<<<(F + 255) / 256, 256, 0, stream>>>(v, f, fdat6, fdat5, vm,
                                                     V, F);

    if (F % 256 == 0) {
        const int FB = F / 256;
        const int PC = 16;
        const int npc = (N + PC - 1) / PC;
        sdf_tr<16><<<FB * npc, 256, 0, stream>>>(p, fdat5, vm, keysP, hitsP,
                                                 N, FB);
        // C = F/16 partial groups
    } else {
        const int CS = (F + C - 1) / C;
        const int npg = (N + 255) / 256;
        sdf_main_g<<<npg * C, 256, 0, stream>>>(p, fdat5, vm, keysP, hitsP,
                                                N, F, C, CS);
    }
    sdf_reduce_epi<<<(N + 63) / 64, 256, 0, stream>>>(p, fdat6, keysP, hitsP,
                                                      out, N, C);
}

// Round 11
// 43.843 us; speedup vs baseline: 1.2141x; 1.0758x over previous
//
#include <hip/hip_runtime.h>
#include <math.h>

#define TRI_EPS 1e-4f
typedef unsigned long long u64;

// ---------- prep (verbatim R8) ----------
__global__ __launch_bounds__(256) void prep_kernel(
    const float* __restrict__ v, const int* __restrict__ f,
    float4* __restrict__ fdat6, float4* __restrict__ fdat5,
    float* __restrict__ vm, int V, int F) {
    const int t = threadIdx.x;
    const int j = blockIdx.x * 256 + t;
    if (j < F) {
        const int i0 = f[3 * j + 0];
        const int i1 = f[3 * j + 1];
        const int i2 = f[3 * j + 2];
        const float ax = v[3 * i0 + 0], ay = v[3 * i0 + 1], az = v[3 * i0 + 2];
        const float bx = v[3 * i1 + 0], by = v[3 * i1 + 1], bz = v[3 * i1 + 2];
        const float cx = v[3 * i2 + 0], cy = v[3 * i2 + 1], cz = v[3 * i2 + 2];
        const float e1x = ax - bx, e1y = ay - by, e1z = az - bz;
        const float e2x = cx - bx, e2y = cy - by, e2z = cz - bz;
        const float e3x = cx - ax, e3y = cy - ay, e3z = cz - az;
        const float m1 = e1x * e1x + e1y * e1y + e1z * e1z;
        const float m2 = e2x * e2x + e2y * e2y + e2z * e2z;
        const float m3 = e3x * e3x + e3y * e3y + e3z * e3z;
        const float inv1 = 1.f / m1, inv2 = 1.f / m2, inv3 = 1.f / m3;
        fdat6[6 * j + 0] = make_float4(ax, ay, az, inv1);
        fdat6[6 * j + 1] = make_float4(bx, by, bz, inv2);
        fdat6[6 * j + 2] = make_float4(cx, cy, cz, inv3);
        fdat6[6 * j + 3] = make_float4(e1x, e1y, e1z, 0.f);
        fdat6[6 * j + 4] = make_float4(e2x, e2y, e2z, 0.f);
        fdat6[6 * j + 5] = make_float4(e3x, e3y, e3z, 0.f);
        fdat5[5 * j + 0] = make_float4(ax, ay, az, inv1);
        fdat5[5 * j + 1] = make_float4(cx, cy, cz, inv2);
        fdat5[5 * j + 2] = make_float4(e1x, e1y, e1z, inv3);
        fdat5[5 * j + 3] = make_float4(e2x, e2y, e2z, 0.f);
        fdat5[5 * j + 4] = make_float4(e3x, e3y, e3z, 0.f);
    }
    if (blockIdx.x == 0) {
        __shared__ float sx[256], sy[256], sz[256];
        float x = 0.f, y = 0.f, z = 0.f;
        for (int i = t; i < V; i += 256) {
            x += v[3 * i + 0];
            y += v[3 * i + 1];
            z += v[3 * i + 2];
        }
        sx[t] = x; sy[t] = y; sz[t] = z;
        __syncthreads();
        for (int off = 128; off > 0; off >>= 1) {
            if (t < off) {
                sx[t] += sx[t + off];
                sy[t] += sy[t + off];
                sz[t] += sz[t + off];
            }
            __syncthreads();
        }
        if (t == 0) {
            vm[0] = sx[0] / (float)V;
            vm[1] = sy[0] / (float)V;
            vm[2] = sz[0] / (float)V;
        }
    }
}

// ---------- verbatim face_point (epilogue only — bit-stable since R2) ------
struct FP {
    float d1, d2, d3;
    float x1, y1, z1, x2, y2, z2, x3, y3, z3;
    float apx, apy, apz;
};

__device__ __forceinline__ FP face_point(
    const float4 ra, const float4 rb, const float4 rc,
    const float e1x, const float e1y, const float e1z,
    const float e2x, const float e2y, const float e2z,
    const float e3x, const float e3y, const float e3z,
    const float px, const float py, const float pz) {
    FP r;
    const float ax = ra.x, ay = ra.y, az = ra.z;
    const float bx = rb.x, by = rb.y, bz = rb.z;
    const float cx = rc.x, cy = rc.y, cz = rc.z;
    r.apx = ax - px; r.apy = ay - py; r.apz = az - pz;
    const float cpx = cx - px, cpy = cy - py, cpz = cz - pz;

    float s1 = (r.apx * e1x + r.apy * e1y + r.apz * e1z) * ra.w;
    s1 = fminf(fmaxf(s1, 0.f), 1.f);
    const float o1 = 1.f - s1;
    r.x1 = s1 * bx + o1 * ax;
    r.y1 = s1 * by + o1 * ay;
    r.z1 = s1 * bz + o1 * az;
    float ux = r.x1 - px, uy = r.y1 - py, uz = r.z1 - pz;
    r.d1 = ux * ux + uy * uy + uz * uz;

    float s2 = (cpx * e2x + cpy * e2y + cpz * e2z) * rb.w;
    s2 = fminf(fmaxf(s2, 0.f), 1.f);
    const float o2 = 1.f - s2;
    r.x2 = s2 * bx + o2 * cx;
    r.y2 = s2 * by + o2 * cy;
    r.z2 = s2 * bz + o2 * cz;
    ux = r.x2 - px; uy = r.y2 - py; uz = r.z2 - pz;
    r.d2 = ux * ux + uy * uy + uz * uz;

    float s3 = (cpx * e3x + cpy * e3y + cpz * e3z) * rc.w;
    s3 = fminf(fmaxf(s3, 0.f), 1.f);
    const float o3 = 1.f - s3;
    r.x3 = s3 * ax + o3 * cx;
    r.y3 = s3 * ay + o3 * cy;
    r.z3 = s3 * az + o3 * cz;
    ux = r.x3 - px; uy = r.y3 - py; uz = r.z3 - pz;
    r.d3 = ux * ux + uy * uy + uz * uz;
    return r;
}

// ---------- lean per-pair update (verbatim R8 expressions) -----------------
__device__ __forceinline__ void pair_lean(
    const float4 r0, const float4 r1, const float4 r2,
    const float4 r3, const float4 r4,
    const float px, const float py, const float pz,
    const float dx, const float dy, const float dz, const int j,
    float& bd2, int& bid, int& hits) {
    const float apx = r0.x - px, apy = r0.y - py, apz = r0.z - pz;
    const float cpx = r1.x - px, cpy = r1.y - py, cpz = r1.z - pz;
    const float e1x = r2.x, e1y = r2.y, e1z = r2.z;
    const float e2x = r3.x, e2y = r3.y, e2z = r3.z;
    const float e3x = r4.x, e3y = r4.y, e3z = r4.z;

    float s1 = (apx * e1x + apy * e1y + apz * e1z) * r0.w;
    s1 = fminf(fmaxf(s1, 0.f), 1.f);
    const float u1x = apx - s1 * e1x;
    const float u1y = apy - s1 * e1y;
    const float u1z = apz - s1 * e1z;
    const float d1 = u1x * u1x + u1y * u1y + u1z * u1z;

    float s2 = (cpx * e2x + cpy * e2y + cpz * e2z) * r1.w;
    s2 = fminf(fmaxf(s2, 0.f), 1.f);
    const float u2x = cpx - s2 * e2x;
    const float u2y = cpy - s2 * e2y;
    const float u2z = cpz - s2 * e2z;
    const float d2 = u2x * u2x + u2y * u2y + u2z * u2z;

    float s3 = (cpx * e3x + cpy * e3y + cpz * e3z) * r2.w;
    s3 = fminf(fmaxf(s3, 0.f), 1.f);
    const float u3x = cpx - s3 * e3x;
    const float u3y = cpy - s3 * e3y;
    const float u3z = cpz - s3 * e3z;
    const float d3 = u3x * u3x + u3y * u3y + u3z * u3z;

    float fd2 = d1; int eid = 0;
    if (d2 < fd2) { fd2 = d2; eid = 1; }
    if (d3 < fd2) { fd2 = d3; eid = 2; }
    if (fd2 < bd2) { bd2 = fd2; bid = (j << 2) | eid; }

    // Moller-Trumbore (VERBATIM — parity must not move)
    const float pvx = dy * e3z - dz * e3y;
    const float pvy = dz * e3x - dx * e3z;
    const float pvz = dx * e3y - dy * e3x;
    const float det = -(e1x * pvx + e1y * pvy + e1z * pvz);
    const float tu = -(apx * pvx + apy * pvy + apz * pvz);
    const float qvx = apy * e1z - apz * e1y;
    const float qvy = apz * e1x - apx * e1z;
    const float qvz = apx * e1y - apy * e1x;
    const float td = dx * qvx + dy * qvy + dz * qvz;
    const float tn = e3x * qvx + e3y * qvy + e3z * qvz;
    const float adet = fabsf(det);
    const float sd = (det > 0.f) ? 1.f : -1.f;
    const float su = tu * sd;
    const float sq = td * sd;
    const float st = tn * sd;
    if (adet > TRI_EPS && su >= 0.f && su <= adet && sq >= 0.f &&
        (su + sq) <= adet && st > TRI_EPS * adet)
        hits++;
}

// ---------- main: 4 points/lane (4 indep dep-chains), LDS faces ------------
template <int CS>
__global__ __launch_bounds__(256) void sdf_main4(
    const float* __restrict__ p, const float4* __restrict__ fd5,
    const float* __restrict__ vm,
    u64* __restrict__ keysP, unsigned* __restrict__ hitsP,
    int N, int C) {
    __shared__ float4 sfd[5 * CS];
    const int t = threadIdx.x;
    const int k = blockIdx.x % C;
    const int pg = blockIdx.x / C;
    const int j0 = k * CS;

    if (t < 5 * CS) sfd[t] = fd5[5 * j0 + t];

    const float vmx = vm[0], vmy = vm[1], vmz = vm[2];
    float px[4], py[4], pz[4], dx[4], dy[4], dz[4], bd2[4];
    int bid[4], hh[4], idx[4];
    bool vld[4];
    #pragma unroll
    for (int q = 0; q < 4; ++q) {
        const int i = pg * 1024 + q * 256 + t;
        idx[q] = i;
        vld[q] = (i < N);
        const int li = vld[q] ? i : 0;
        px[q] = p[3 * li + 0];
        py[q] = p[3 * li + 1];
        pz[q] = p[3 * li + 2];
        dx[q] = vmx - px[q];
        dy[q] = vmy - py[q];
        dz[q] = vmz - pz[q];
        bd2[q] = INFINITY;
        bid[q] = 0x7fffffff;
        hh[q] = 0;
    }
    __syncthreads();

    for (int jj = 0; jj < CS; ++jj) {
        const float4 r0 = sfd[5 * jj + 0];
        const float4 r1 = sfd[5 * jj + 1];
        const float4 r2 = sfd[5 * jj + 2];
        const float4 r3 = sfd[5 * jj + 3];
        const float4 r4 = sfd[5 * jj + 4];
        const int j = j0 + jj;
        #pragma unroll
        for (int q = 0; q < 4; ++q) {
            pair_lean(r0, r1, r2, r3, r4, px[q], py[q], pz[q],
                      dx[q], dy[q], dz[q], j, bd2[q], bid[q], hh[q]);
        }
    }

    #pragma unroll
    for (int q = 0; q < 4; ++q) {
        if (vld[q]) {
            keysP[(size_t)k * N + idx[q]] =
                ((u64)__float_as_uint(bd2[q]) << 32) | (unsigned)bid[q];
            hitsP[(size_t)k * N + idx[q]] = (unsigned)hh[q];
        }
    }
}

// ---------- generic fallback (runtime CS, 1 pt/lane) -----------------------
__global__ __launch_bounds__(256) void sdf_main_g(
    const float* __restrict__ p, const float4* __restrict__ fd5,
    const float* __restrict__ vm,
    u64* __restrict__ keysP, unsigned* __restrict__ hitsP,
    int N, int F, int C, int CS) {
    const int k = blockIdx.x % C;
    const int pg = blockIdx.x / C;
    const int i = pg * 256 + threadIdx.x;
    if (i >= N) return;
    const float px = p[3 * i + 0];
    const float py = p[3 * i + 1];
    const float pz = p[3 * i + 2];
    const float dx = vm[0] - px;
    const float dy = vm[1] - py;
    const float dz = vm[2] - pz;
    float bd2 = INFINITY; int bid = 0x7fffffff; int hits = 0;
    const int j0 = k * CS;
    const int j1 = min(F, j0 + CS);
    for (int j = j0; j < j1; ++j) {
        pair_lean(fd5[5 * j + 0], fd5[5 * j + 1], fd5[5 * j + 2],
                  fd5[5 * j + 3], fd5[5 * j + 4],
                  px, py, pz, dx, dy, dz, j, bd2, bid, hits);
    }
    keysP[(size_t)k * N + i] =
        ((u64)__float_as_uint(bd2) << 32) | (unsigned)bid;
    hitsP[(size_t)k * N + i] = (unsigned)hits;
}

// ---------- reduce (C=256) + verbatim epilogue: 16 pts x 16 k-slots --------
__global__ __launch_bounds__(256) void sdf_reduce_epi16(
    const float* __restrict__ p, const float4* __restrict__ fd6,
    const u64* __restrict__ keysP, const unsigned* __restrict__ hitsP,
    float* __restrict__ out, int N, int C) {
    const int t = threadIdx.x;
    const int ii = t & 15;
    const int ks = t >> 4;                 // 16 k-slots
    const int i = blockIdx.x * 16 + ii;

    u64 bk = 0xFFFFFFFFFFFFFFFFull;
    unsigned hs = 0;
    if (i < N) {
        const int kspan = C >> 4;          // chunks per slot
        for (int kk = 0; kk < kspan; ++kk) {
            const int k = ks + kk * 16;
            const u64 kv = keysP[(size_t)k * N + i];   // 128B coalesced/16-grp
            if (kv < bk) bk = kv;
            hs += hitsP[(size_t)k * N + i];
        }
    }
    __shared__ u64 sk[16][17];
    __shared__ unsigned sh[16][17];
    sk[ks][ii] = bk;
    sh[ks][ii] = hs;
    __syncthreads();
    for (int off = 8; off > 0; off >>= 1) {
        if (ks < off) {
            const u64 kv = sk[ks + off][ii];
            if (kv < sk[ks][ii]) sk[ks][ii] = kv;
            sh[ks][ii] += sh[ks + off][ii];
        }
        __syncthreads();
    }
    if (t < 16 && i < N) {
        const u64 key = sk[0][t];
        const unsigned hits = sh[0][t];
        const float bd2 = __uint_as_float((unsigned)(key >> 32));
        const int bid = (int)(unsigned)(key & 0xFFFFFFFFull);
        const int jw = bid >> 2;
        const int eid = bid & 3;
        const float px = p[3 * i + 0];
        const float py = p[3 * i + 1];
        const float pz = p[3 * i + 2];
        const float4 wa  = fd6[6 * jw + 0];
        const float4 wb  = fd6[6 * jw + 1];
        const float4 wc  = fd6[6 * jw + 2];
        const float4 we1 = fd6[6 * jw + 3];
        const float4 we2 = fd6[6 * jw + 4];
        const float4 we3 = fd6[6 * jw + 5];
        const FP r = face_point(wa, wb, wc, we1.x, we1.y, we1.z,
                                we2.x, we2.y, we2.z, we3.x, we3.y, we3.z,
                                px, py, pz);
        float clx = r.x1, cly = r.y1, clz = r.z1;
        if (eid == 1) { clx = r.x2; cly = r.y2; clz = r.z2; }
        if (eid == 2) { clx = r.x3; cly = r.y3; clz = r.z3; }
        const float d = sqrtf(bd2);
        out[i] = (hits & 1u) ? -d : d;
        out[N + 3 * i + 0] = clx;
        out[N + 3 * i + 1] = cly;
        out[N + 3 * i + 2] = clz;
    }
}

extern "C" void kernel_launch(void* const* d_in, const int* in_sizes, int n_in,
                              void* d_out, int out_size, void* d_ws,
                              size_t ws_size, hipStream_t stream) {
    const float* p = (const float*)d_in[0];
    const float* v = (const float*)d_in[1];
    const int* f = (const int*)d_in[2];
    float* out = (float*)d_out;

    const int N = in_sizes[0] / 3;
    const int V = in_sizes[1] / 3;
    const int F = in_sizes[2] / 3;

    const int C = 256;   // face chunks (reduce kernel assumes multiple of 16)
    const int CS = 16;   // faces per chunk on template path (F == 4096)

    // ws: vm[4] | keysP[C*N] u64 | hitsP[C*N] u32 | fdat6[6F] | fdat5[5F]
    char* base = (char*)d_ws;
    float* vm = (float*)base;
    u64* keysP = (u64*)(base + 16);
    unsigned* hitsP = (unsigned*)(base + 16 + 8ull * C * N);
    size_t off = 16 + 12ull * C * N;
    off = (off + 15) & ~15ull;
    float4* fdat6 = (float4*)(base + off);
    float4* fdat5 = (float4*)(base + off + 6ull * F * sizeof(float4));

    prep_kernel<<<(F + 255) / 256, 256, 0, stream>>>(v, f, fdat6, fdat5, vm,
                                                     V, F);

    if (F == C * CS) {
        const int pgs = (N + 1023) / 1024;
        sdf_main4<16><<<pgs * C, 256, 0, stream>>>(p, fdat5, vm, keysP, hitsP,
                                                   N, C);
    } else {
        const int CSg = (F + C - 1) / C;
        const int npg = (N + 255) / 256;
        sdf_main_g<<<npg * C, 256, 0, stream>>>(p, fdat5, vm, keysP, hitsP,
                                                N, F, C, CSg);
    }
    sdf_reduce_epi16<<<(N + 15) / 16, 256, 0, stream>>>(p, fdat6, keysP, hitsP,
                                                        out, N, C);
}